// Round 1
// baseline (626.383 us; speedup 1.0000x reference)
//
#include <hip/hip_runtime.h>
#include <hip/hip_bf16.h>

// Problem constants (fixed by setup_inputs)
constexpr int Bn   = 32;
constexpr int CIN  = 128;
constexpr int Hh   = 56;
constexpr int Ww   = 56;
constexpr int HW   = Hh * Ww;      // 3136
constexpr int COUT = 128;
constexpr int En   = 8;

struct GateInfo { int e0, e1; float w0, w1; };

// ---------------- Kernel 1: global average pool ----------------
// grid = Bn*CIN blocks, 256 threads; one block reduces one (b,c) plane.
__global__ void gap_kernel(const float* __restrict__ x, float* __restrict__ gap) {
    int bc = blockIdx.x;
    const float* p = x + (size_t)bc * HW;
    float s = 0.f;
    for (int i = threadIdx.x; i < HW; i += 256) s += p[i];
    #pragma unroll
    for (int off = 32; off; off >>= 1) s += __shfl_down(s, off, 64);
    __shared__ float red[4];
    if ((threadIdx.x & 63) == 0) red[threadIdx.x >> 6] = s;
    __syncthreads();
    if (threadIdx.x == 0) {
        float t = red[0] + red[1] + red[2] + red[3];
        gap[bc] = t / (float)HW;
    }
}

// ---------------- Kernel 2: gate (logits -> top2 -> softmax) ----------------
// single block, 256 threads. thread t: (b = t/8, e = t%8) computes one logit.
__global__ void gate_kernel(const float* __restrict__ gap,
                            const float* __restrict__ gate_w,
                            const float* __restrict__ gate_b,
                            float* __restrict__ wout,      // [Bn*En] weights output
                            GateInfo* __restrict__ info) {
    __shared__ float logits[Bn][En];
    __shared__ GateInfo gi[Bn];
    int tid = threadIdx.x;
    int b = tid >> 3, e = tid & 7;
    float s = gate_b[e];
    const float* g = gap + b * CIN;
    const float* w = gate_w + e * CIN;
    #pragma unroll 8
    for (int c = 0; c < CIN; c++) s += g[c] * w[c];
    logits[b][e] = s;
    __syncthreads();
    if (tid < Bn) {
        float v[En];
        #pragma unroll
        for (int k = 0; k < En; k++) v[k] = logits[tid][k];
        int i0 = 0; float m0 = v[0];
        #pragma unroll
        for (int k = 1; k < En; k++) if (v[k] > m0) { m0 = v[k]; i0 = k; }
        int i1 = -1; float m1 = -1e30f;
        #pragma unroll
        for (int k = 0; k < En; k++) if (k != i0 && v[k] > m1) { m1 = v[k]; i1 = k; }
        float ex = expf(m1 - m0);
        float den = 1.f + ex;
        GateInfo t; t.e0 = i0; t.e1 = i1; t.w0 = 1.f / den; t.w1 = ex / den;
        gi[tid] = t;
        info[tid] = t;
    }
    __syncthreads();
    {
        int bb = tid >> 3, ee = tid & 7;
        GateInfo t = gi[bb];
        float val = (ee == t.e0) ? t.w0 : (ee == t.e1) ? t.w1 : 0.f;
        wout[tid] = val;
    }
}

// ---------------- Kernel 3: per-sample combined-weight 3x3 conv ----------------
// Block: (b, cout block of 64, row block of 4). 256 threads.
// Thread: local cout = tid/4, w-quarter = tid%3 -> 4 rows x 14 w outputs.
constexpr int CC  = 8;    // cins staged per chunk
constexpr int RB  = 4;    // output rows per block
constexpr int COB = 64;   // couts per block

__global__ __launch_bounds__(256, 2) void conv_kernel(
        const float* __restrict__ x, const float* __restrict__ cw,
        const GateInfo* __restrict__ info, float* __restrict__ out) {
    __shared__ float xs[CC][6][64];      // input rows (col = w+1, halo-padded)
    __shared__ float wl[CC][COB][12];    // combined weights (9 used, pad to 12)

    int gid = blockIdx.x;
    int b   = gid / 28;
    int rem = gid % 28;
    int cb  = rem / 14;
    int rb  = rem % 14;
    int row0  = rb * RB;
    int cout0 = cb * COB;
    int tid = threadIdx.x;
    int coL = tid >> 2;           // 0..63
    int wq  = tid & 3;
    int wbase = wq * 14;          // 0,14,28,42 (even -> float2 aligned)

    GateInfo gi = info[b];
    const float* xb  = x  + (size_t)b * CIN * HW;
    const float* w0p = cw + (size_t)gi.e0 * COUT * CIN * 9;
    const float* w1p = cw + (size_t)gi.e1 * COUT * CIN * 9;

    float acc[RB][14];
    #pragma unroll
    for (int r = 0; r < RB; r++)
        #pragma unroll
        for (int i = 0; i < 14; i++) acc[r][i] = 0.f;

    for (int c0 = 0; c0 < CIN; c0 += CC) {
        __syncthreads();
        // stage input: CC cins x 6 rows x 64 cols = 3072 elems, 12/thread
        #pragma unroll
        for (int i = 0; i < 12; i++) {
            int idx = i * 256 + tid;
            int c   = idx / 384;
            int r6  = (idx % 384) / 64;
            int col = idx & 63;
            int grow = row0 - 1 + r6;
            int gw   = col - 1;
            float v = 0.f;
            if ((unsigned)grow < 56u && (unsigned)gw < 56u)
                v = xb[(size_t)(c0 + c) * HW + grow * 56 + gw];
            xs[c][r6][col] = v;
        }
        // stage combined weights: CC x 64 x 9 = 4608 elems, 18/thread
        #pragma unroll
        for (int i = 0; i < 18; i++) {
            int idx = i * 256 + tid;
            int c    = idx / 576;
            int rem2 = idx % 576;
            int co   = rem2 / 9;
            int k    = rem2 % 9;
            size_t o = ((size_t)(cout0 + co) * CIN + c0 + c) * 9 + k;
            wl[c][co][k] = gi.w0 * w0p[o] + gi.w1 * w1p[o];
        }
        __syncthreads();
        // compute
        #pragma unroll
        for (int c = 0; c < CC; c++) {
            float wr[9];
            #pragma unroll
            for (int k = 0; k < 9; k++) wr[k] = wl[c][coL][k];
            float xr[3][16];
            #pragma unroll
            for (int j = 0; j < 3; j++) {
                const float2* p = (const float2*)&xs[c][j][wbase];
                #pragma unroll
                for (int t = 0; t < 8; t++) { float2 v = p[t]; xr[j][2*t] = v.x; xr[j][2*t+1] = v.y; }
            }
            #pragma unroll
            for (int r = 0; r < RB; r++) {
                #pragma unroll
                for (int dr = 0; dr < 3; dr++) {
                    int sr = (r + dr) % 3;    // rolling slot holding row r+dr
                    #pragma unroll
                    for (int dw = 0; dw < 3; dw++) {
                        float wv = wr[dr * 3 + dw];
                        #pragma unroll
                        for (int i = 0; i < 14; i++)
                            acc[r][i] = fmaf(wv, xr[sr][i + dw], acc[r][i]);
                    }
                }
                if (r < RB - 1) {
                    int j = r + 3;            // next input row -> slot r%3
                    int slot = r % 3;
                    const float2* p = (const float2*)&xs[c][j][wbase];
                    #pragma unroll
                    for (int t = 0; t < 8; t++) { float2 v = p[t]; xr[slot][2*t] = v.x; xr[slot][2*t+1] = v.y; }
                }
            }
        }
    }
    // epilogue
    float* ob = out + ((size_t)b * COUT + cout0 + coL) * HW;
    #pragma unroll
    for (int r = 0; r < RB; r++)
        #pragma unroll
        for (int i = 0; i < 14; i++)
            ob[(row0 + r) * 56 + wbase + i] = acc[r][i];
}

// ---------------- launch ----------------
extern "C" void kernel_launch(void* const* d_in, const int* in_sizes, int n_in,
                              void* d_out, int out_size, void* d_ws, size_t ws_size,
                              hipStream_t stream) {
    const float* x  = (const float*)d_in[0];
    const float* cw = (const float*)d_in[1];
    const float* gw = (const float*)d_in[2];
    const float* gb = (const float*)d_in[3];
    // d_in[4] = top_k (==2, fixed by setup)

    float* out  = (float*)d_out;
    float* gap  = (float*)d_ws;                          // Bn*CIN floats
    GateInfo* info = (GateInfo*)((char*)d_ws + 16384);   // 32 * 16B
    float* wout = out + (size_t)Bn * COUT * HW;          // weights section of d_out

    gap_kernel <<<Bn * CIN, 256, 0, stream>>>(x, gap);
    gate_kernel<<<1,        256, 0, stream>>>(gap, gw, gb, wout, info);
    conv_kernel<<<Bn * 2 * 14, 256, 0, stream>>>(x, cw, info, out);
}

// Round 2
// 182.027 us; speedup vs baseline: 3.4412x; 3.4412x over previous
//
#include <hip/hip_runtime.h>
#include <hip/hip_bf16.h>

constexpr int Bn   = 32;
constexpr int CIN  = 128;
constexpr int Hh   = 56;
constexpr int Ww   = 56;
constexpr int HW   = Hh * Ww;      // 3136
constexpr int COUT = 128;
constexpr int En   = 8;

typedef __attribute__((ext_vector_type(8))) short bf16x8;   // 8 bf16 (4 VGPRs)
typedef __attribute__((ext_vector_type(4))) float f32x4;

struct GateInfo { int e0, e1; float w0, w1; };

// ---- workspace layout (bytes) ----
constexpr size_t XB_OFF  = 0;                               // bf16 NHWC x
constexpr size_t XB_SZ   = (size_t)Bn * HW * CIN * 2;       // 25,690,112
constexpr size_t WW_OFF  = XB_OFF + XB_SZ;                  // bf16 combined W [b][tap][cout][cin]
constexpr size_t WW_SZ   = (size_t)Bn * 9 * COUT * CIN * 2; // 9,437,184
constexpr size_t HS_OFF  = WW_OFF + WW_SZ;                  // f32 per-(b,h,c) row sums
constexpr size_t HS_SZ   = (size_t)Bn * Hh * CIN * 4;       // 917,504
constexpr size_t GAP_OFF = HS_OFF + HS_SZ;                  // f32 gap [b][c]
constexpr size_t GAP_SZ  = (size_t)Bn * CIN * 4;
constexpr size_t GI_OFF  = GAP_OFF + GAP_SZ;                // GateInfo[32]

// ---------------- 1: NCHW f32 -> NHWC bf16, fused per-row sums ----------------
// grid = Bn*Hh blocks (b,h), 256 threads
__global__ __launch_bounds__(256) void convert_kernel(const float* __restrict__ x,
        __hip_bfloat16* __restrict__ xbf, float* __restrict__ hsum) {
    __shared__ float lt[CIN * 57];   // pad 57 to kill transpose bank conflicts
    int gid = blockIdx.x;
    int b = gid / Hh, h = gid % Hh;
    const float* xp = x + (size_t)b * CIN * HW + h * Ww;
    for (int u = threadIdx.x; u < CIN * Ww; u += 256) {
        int c = u / Ww, w = u % Ww;
        lt[c * 57 + w] = xp[(size_t)c * HW + w];
    }
    __syncthreads();
    __hip_bfloat16* xo = xbf + ((size_t)b * HW + h * Ww) * CIN;
    for (int u = threadIdx.x; u < CIN * Ww; u += 256) {
        int w = u >> 7, c = u & 127;               // consecutive lanes -> consecutive c -> coalesced
        xo[u] = __float2bfloat16(lt[c * 57 + w]);
    }
    if (threadIdx.x < CIN) {
        int c = threadIdx.x;
        float s = 0.f;
        #pragma unroll 8
        for (int w = 0; w < Ww; w++) s += lt[c * 57 + w];
        hsum[((size_t)b * Hh + h) * CIN + c] = s;
    }
}

// ---------------- 2: finish GAP ----------------
__global__ void gap2_kernel(const float* __restrict__ hsum, float* __restrict__ gap) {
    int t = blockIdx.x * 256 + threadIdx.x;        // 4096 = Bn*CIN
    int b = t >> 7, c = t & 127;
    float s = 0.f;
    for (int h = 0; h < Hh; h++) s += hsum[((size_t)b * Hh + h) * CIN + c];
    gap[t] = s * (1.f / (float)HW);
}

// ---------------- 3: gate (logits -> top2 -> softmax) ----------------
__global__ void gate_kernel(const float* __restrict__ gap,
                            const float* __restrict__ gate_w,
                            const float* __restrict__ gate_b,
                            float* __restrict__ wout,
                            GateInfo* __restrict__ info) {
    __shared__ float logits[Bn][En];
    __shared__ GateInfo gi[Bn];
    int tid = threadIdx.x;
    int b = tid >> 3, e = tid & 7;
    float s = gate_b[e];
    const float* g = gap + b * CIN;
    const float* w = gate_w + e * CIN;
    #pragma unroll 8
    for (int c = 0; c < CIN; c++) s += g[c] * w[c];
    logits[b][e] = s;
    __syncthreads();
    if (tid < Bn) {
        float v[En];
        #pragma unroll
        for (int k = 0; k < En; k++) v[k] = logits[tid][k];
        int i0 = 0; float m0 = v[0];
        #pragma unroll
        for (int k = 1; k < En; k++) if (v[k] > m0) { m0 = v[k]; i0 = k; }
        int i1 = -1; float m1 = -1e30f;
        #pragma unroll
        for (int k = 0; k < En; k++) if (k != i0 && v[k] > m1) { m1 = v[k]; i1 = k; }
        float ex = expf(m1 - m0);
        float den = 1.f + ex;
        GateInfo t; t.e0 = i0; t.e1 = i1; t.w0 = 1.f / den; t.w1 = ex / den;
        gi[tid] = t;
        info[tid] = t;
    }
    __syncthreads();
    {
        int bb = tid >> 3, ee = tid & 7;
        GateInfo t = gi[bb];
        wout[tid] = (ee == t.e0) ? t.w0 : (ee == t.e1) ? t.w1 : 0.f;
    }
}

// ---------------- 4: combined weights -> bf16 [b][tap][cout][cin] ----------------
// grid = Bn*8 blocks (b, cout-group of 16), 256 threads
__global__ __launch_bounds__(256) void wcomb_kernel(const float* __restrict__ cw,
        const GateInfo* __restrict__ info, __hip_bfloat16* __restrict__ wws) {
    __shared__ __hip_bfloat16 wl[16 * 1152];       // [co][cin][tap]
    int b = blockIdx.x >> 3, cg = blockIdx.x & 7;
    GateInfo gi = info[b];
    const float* p0 = cw + (size_t)gi.e0 * COUT * CIN * 9 + (size_t)cg * 16 * 1152;
    const float* p1 = cw + (size_t)gi.e1 * COUT * CIN * 9 + (size_t)cg * 16 * 1152;
    for (int u = threadIdx.x; u < 16 * 1152; u += 256)
        wl[u] = __float2bfloat16(gi.w0 * p0[u] + gi.w1 * p1[u]);
    __syncthreads();
    __hip_bfloat16* wo = wws + (size_t)b * 9 * COUT * CIN + (size_t)cg * 16 * CIN;
    for (int u = threadIdx.x; u < 16 * 1152; u += 256) {
        int t = u / 2048, rem = u & 2047;
        int co = rem >> 7, cin = rem & 127;
        wo[(size_t)t * COUT * CIN + co * CIN + cin] = wl[co * 1152 + cin * 9 + t];
    }
}

// ---------------- 5: implicit-GEMM conv via MFMA ----------------
// Block: (b, cout half of 64, row block of 4) -> grid 32*2*14 = 896, 256 thr = 4 waves.
// Wave grid 2x2: wave tile M=32 x N=112 -> acc = 2 Mtiles x 7 Ntiles of 16x16.
// LDS X chunk: 32 cins x 6 rows x 58 cols, stored as 4 k-group planes of
// 16B units (unit = 8 cins for one (row,col)), plane stride US units.
constexpr int US = 349;   // 349 mod 8 = 5 -> bank-group spread

__global__ __launch_bounds__(256, 2) void conv_mfma(
        const __hip_bfloat16* __restrict__ xbf,
        const __hip_bfloat16* __restrict__ wws,
        float* __restrict__ out) {
    __shared__ char xs[4 * US * 16];               // 22,336 B

    int gid = blockIdx.x;
    int b = gid / 28, rem = gid % 28;
    int cb = rem / 14, rb = rem % 14;
    int row0 = rb * 4, cout0 = cb * 64;
    int tid = threadIdx.x, wave = tid >> 6, lane = tid & 63;
    int wm = wave >> 1, wn = wave & 1;
    int l15 = lane & 15, lk = lane >> 4;

    // per-lane LDS byte base for each N-tile (B fragment), tap adds a constant
    int bbase[7];
    #pragma unroll
    for (int i = 0; i < 7; i++) {
        int p = wn * 112 + i * 16 + l15;           // pixel within the 224-span
        int r = p / 56, c = p % 56;
        bbase[i] = (lk * US + (r * 58 + c)) * 16;
    }

    const __hip_bfloat16* wwb = wws + (size_t)b * 9 * COUT * CIN;
    int arow = cout0 + wm * 32 + l15;

    f32x4 acc[2][7];
    #pragma unroll
    for (int mt = 0; mt < 2; mt++)
        #pragma unroll
        for (int i = 0; i < 7; i++) acc[mt][i] = (f32x4){0.f, 0.f, 0.f, 0.f};

    for (int c0 = 0; c0 < CIN; c0 += 32) {
        __syncthreads();
        // stage 32 cins x 6 rows x 58 cols (halo zero-filled): 1392 16B units
        const __hip_bfloat16* xbb = xbf + (size_t)b * HW * CIN + c0;
        for (int u = tid; u < 1392; u += 256) {
            int rc = u >> 2, ul = u & 3;
            int lr = rc / 58, lc = rc % 58;
            int grow = row0 - 1 + lr, gw = lc - 1;
            int4 v = {0, 0, 0, 0};
            if ((unsigned)grow < 56u && (unsigned)gw < 56u)
                v = *(const int4*)(xbb + ((size_t)grow * 56 + gw) * CIN + ul * 8);
            *(int4*)(xs + (ul * US + rc) * 16) = v;
        }
        __syncthreads();

        const __hip_bfloat16* ap = wwb + (size_t)arow * CIN + c0 + lk * 8;
        #pragma unroll
        for (int t = 0; t < 9; t++) {
            const int dr = t / 3, dc = t % 3;
            bf16x8 a0 = *(const bf16x8*)(ap + (size_t)t * COUT * CIN);
            bf16x8 a1 = *(const bf16x8*)(ap + (size_t)t * COUT * CIN + 16 * CIN);
            const int toff = (dr * 58 + dc) * 16;
            #pragma unroll
            for (int i = 0; i < 7; i++) {
                bf16x8 bv = *(const bf16x8*)(xs + bbase[i] + toff);
                acc[0][i] = __builtin_amdgcn_mfma_f32_16x16x32_bf16(a0, bv, acc[0][i], 0, 0, 0);
                acc[1][i] = __builtin_amdgcn_mfma_f32_16x16x32_bf16(a1, bv, acc[1][i], 0, 0, 0);
            }
        }
    }

    // epilogue: C/D layout col=lane&15 (pixel), row=(lane>>4)*4+j (cout)
    float* outb = out + (size_t)b * COUT * HW + row0 * 56;
    #pragma unroll
    for (int mt = 0; mt < 2; mt++) {
        int cbase = cout0 + wm * 32 + mt * 16 + lk * 4;
        #pragma unroll
        for (int i = 0; i < 7; i++) {
            int pp = wn * 112 + i * 16 + l15;
            #pragma unroll
            for (int j = 0; j < 4; j++)
                outb[(size_t)(cbase + j) * HW + pp] = acc[mt][i][j];
        }
    }
}

// ---------------- launch ----------------
extern "C" void kernel_launch(void* const* d_in, const int* in_sizes, int n_in,
                              void* d_out, int out_size, void* d_ws, size_t ws_size,
                              hipStream_t stream) {
    const float* x  = (const float*)d_in[0];
    const float* cw = (const float*)d_in[1];
    const float* gw = (const float*)d_in[2];
    const float* gb = (const float*)d_in[3];

    float* out = (float*)d_out;
    char* ws = (char*)d_ws;
    __hip_bfloat16* xbf  = (__hip_bfloat16*)(ws + XB_OFF);
    __hip_bfloat16* wws  = (__hip_bfloat16*)(ws + WW_OFF);
    float* hsum          = (float*)(ws + HS_OFF);
    float* gap           = (float*)(ws + GAP_OFF);
    GateInfo* info       = (GateInfo*)(ws + GI_OFF);
    float* wout = out + (size_t)Bn * COUT * HW;

    convert_kernel<<<Bn * Hh, 256, 0, stream>>>(x, xbf, hsum);
    gap2_kernel   <<<16,      256, 0, stream>>>(hsum, gap);
    gate_kernel   <<<1,       256, 0, stream>>>(gap, gw, gb, wout, info);
    wcomb_kernel  <<<Bn * 8,  256, 0, stream>>>(cw, info, wws);
    conv_mfma     <<<Bn * 2 * 14, 256, 0, stream>>>(xbf, wws, out);
}